// Round 1
// baseline (318.438 us; speedup 1.0000x reference)
//
#include <hip/hip_runtime.h>
#include <math.h>

// Problem constants
#define NRES 384
#define CS   384
#define CZ   128
#define NH   12
#define CDIM 16
#define NQP  4
#define NPV  8

__device__ __constant__ float kWL = 0.5773502691896258f;   // sqrt(1/3)
#define WLc 0.5773502691896258f
#define WCc 0.23570226039551587f                            // sqrt(2/(9*4))

// workspace layout (floats)
#define OFF_Q    0
#define OFF_K    73728
#define OFF_V    147456
#define OFF_QP   221184
#define OFF_KP   276480
#define OFF_VP   331776
#define OFF_QE   442368     // (12,384,32)
#define OFF_KE   589824     // (12,384,32)
#define OFF_VE   737280     // (12,384,40)
#define OFF_BIAS 921600     // (12,384,384)  wl*(z@Wb+bb)
#define OFF_CAT  2691072    // (384,2112)
// total 3502080 floats = 14,008,320 bytes

// ---------------------------------------------------------------------------
// Kernel 1: fused projection GEMM  s(384x384) @ {Wq,Wk,Wv,Wqp,Wkp,Wvp} + bias
// BM=BN=32, BK=16, 2x2 micro tile, 256 threads. Virtual n-tiles:
// [0,6)=Wq [6,12)=Wk [12,18)=Wv [18,23)=Wqp(144) [23,28)=Wkp(144) [28,37)=Wvp(288)
// ---------------------------------------------------------------------------
__global__ __launch_bounds__(256) void proj_kernel(
    const float* __restrict__ s,
    const float* __restrict__ Wq,  const float* __restrict__ bq,
    const float* __restrict__ Wk,  const float* __restrict__ bk,
    const float* __restrict__ Wv,  const float* __restrict__ bv,
    const float* __restrict__ Wqp, const float* __restrict__ bqp,
    const float* __restrict__ Wkp, const float* __restrict__ bkp,
    const float* __restrict__ Wvp, const float* __restrict__ bvp,
    float* __restrict__ ws)
{
    int tn = blockIdx.x;   // 0..36
    int tm = blockIdx.y;   // 0..11
    const float* W; const float* bias; float* outp; int dout; int col0;
    if (tn < 6)       { W = Wq;  bias = bq;  outp = ws + OFF_Q;  dout = 192; col0 = tn * 32; }
    else if (tn < 12) { W = Wk;  bias = bk;  outp = ws + OFF_K;  dout = 192; col0 = (tn - 6) * 32; }
    else if (tn < 18) { W = Wv;  bias = bv;  outp = ws + OFF_V;  dout = 192; col0 = (tn - 12) * 32; }
    else if (tn < 23) { W = Wqp; bias = bqp; outp = ws + OFF_QP; dout = 144; col0 = (tn - 18) * 32; }
    else if (tn < 28) { W = Wkp; bias = bkp; outp = ws + OFF_KP; dout = 144; col0 = (tn - 23) * 32; }
    else              { W = Wvp; bias = bvp; outp = ws + OFF_VP; dout = 288; col0 = (tn - 28) * 32; }

    __shared__ float sA[16][33];   // [k][i]
    __shared__ float sB[16][33];   // [k][j]
    int t  = threadIdx.x;
    int tx = t & 15, ty = t >> 4;
    int m0 = tm * 32;
    float acc00 = 0.f, acc01 = 0.f, acc10 = 0.f, acc11 = 0.f;

    for (int k0 = 0; k0 < CS; k0 += 16) {
        __syncthreads();
        #pragma unroll
        for (int q = 0; q < 2; q++) {
            int e  = t + 256 * q;
            int il = e >> 4, kl = e & 15;
            sA[kl][il] = s[(m0 + il) * CS + k0 + kl];
            int kl2 = e >> 5, jl = e & 31;
            int c   = col0 + jl;
            sB[kl2][jl] = (c < dout) ? W[(k0 + kl2) * dout + c] : 0.0f;
        }
        __syncthreads();
        #pragma unroll
        for (int k = 0; k < 16; k++) {
            float a0 = sA[k][ty * 2], a1 = sA[k][ty * 2 + 1];
            float b0 = sB[k][tx * 2], b1 = sB[k][tx * 2 + 1];
            acc00 += a0 * b0; acc01 += a0 * b1;
            acc10 += a1 * b0; acc11 += a1 * b1;
        }
    }
    int r0 = m0 + ty * 2, r1 = r0 + 1;
    int c0 = col0 + tx * 2, c1 = c0 + 1;
    if (c0 < dout) { outp[r0 * dout + c0] = acc00 + bias[c0]; outp[r1 * dout + c0] = acc10 + bias[c0]; }
    if (c1 < dout) { outp[r0 * dout + c1] = acc01 + bias[c1]; outp[r1 * dout + c1] = acc11 + bias[c1]; }
}

// ---------------------------------------------------------------------------
// Kernel 2: per-(h,i) prep — transform points, build extended Q/K (32-dim) and
// V_ext (40-dim: 16 v + 24 transformed v-points).
// Logit decomposition: wl*(qk + bias - g*(wc/2)*(sqq + sqk - 2*dot12))
//   Qe = [wl*0.25*q(16), wl*g*wc*tqp(12), -wl*g*wc/2, -wl*g*wc/2*sqq, 0, 0]
//   Ke = [k(16),          tkp(12),         sqk,        1,             0, 0]
// ---------------------------------------------------------------------------
__global__ __launch_bounds__(256) void prep_kernel(
    const float* __restrict__ T, const float* __restrict__ hw,
    float* __restrict__ ws)
{
    int id = blockIdx.x * 256 + threadIdx.x;
    if (id >= NH * NRES) return;
    int h = id / NRES, i = id % NRES;

    const float* q_raw  = ws + OFF_Q;
    const float* k_raw  = ws + OFF_K;
    const float* v_raw  = ws + OFF_V;
    const float* qp_raw = ws + OFF_QP;
    const float* kp_raw = ws + OFF_KP;
    const float* vp_raw = ws + OFF_VP;

    float R[3][3], tr[3];
    #pragma unroll
    for (int r = 0; r < 3; r++) {
        #pragma unroll
        for (int c = 0; c < 3; c++) R[r][c] = T[i * 16 + r * 4 + c];
        tr[r] = T[i * 16 + r * 4 + 3];
    }
    float x = hw[h];
    float g = (x > 20.f) ? x : log1pf(expf(x));   // softplus

    float* Qe = ws + OFF_QE + (size_t)(h * NRES + i) * 32;
    float* Ke = ws + OFF_KE + (size_t)(h * NRES + i) * 32;
    #pragma unroll
    for (int c = 0; c < 16; c++) {
        Qe[c] = WLc * 0.25f * q_raw[i * 192 + h * 16 + c];
        Ke[c] = k_raw[i * 192 + h * 16 + c];
    }
    float sqq = 0.f, sqk = 0.f;
    float gw = WLc * g * WCc;
    #pragma unroll
    for (int p = 0; p < NQP; p++) {
        float a0 = qp_raw[i * 144 + 0 * 48 + h * 4 + p];
        float a1 = qp_raw[i * 144 + 1 * 48 + h * 4 + p];
        float a2 = qp_raw[i * 144 + 2 * 48 + h * 4 + p];
        float b0 = kp_raw[i * 144 + 0 * 48 + h * 4 + p];
        float b1 = kp_raw[i * 144 + 1 * 48 + h * 4 + p];
        float b2 = kp_raw[i * 144 + 2 * 48 + h * 4 + p];
        #pragma unroll
        for (int r = 0; r < 3; r++) {
            float tq = R[r][0] * a0 + R[r][1] * a1 + R[r][2] * a2 + tr[r];
            float tk = R[r][0] * b0 + R[r][1] * b1 + R[r][2] * b2 + tr[r];
            Qe[16 + p * 3 + r] = gw * tq;
            Ke[16 + p * 3 + r] = tk;
            sqq += tq * tq;
            sqk += tk * tk;
        }
    }
    Qe[28] = -0.5f * gw;
    Qe[29] = -0.5f * gw * sqq;
    Qe[30] = 0.f; Qe[31] = 0.f;
    Ke[28] = sqk;
    Ke[29] = 1.f;
    Ke[30] = 0.f; Ke[31] = 0.f;

    float* Ve = ws + OFF_VE + (size_t)(h * NRES + i) * 40;
    #pragma unroll
    for (int c = 0; c < 16; c++) Ve[c] = v_raw[i * 192 + h * 16 + c];
    #pragma unroll
    for (int p = 0; p < NPV; p++) {
        float a0 = vp_raw[i * 288 + 0 * 96 + h * 8 + p];
        float a1 = vp_raw[i * 288 + 1 * 96 + h * 8 + p];
        float a2 = vp_raw[i * 288 + 2 * 96 + h * 8 + p];
        #pragma unroll
        for (int r = 0; r < 3; r++)
            Ve[16 + p * 3 + r] = R[r][0] * a0 + R[r][1] * a1 + R[r][2] * a2 + tr[r];
    }
}

// ---------------------------------------------------------------------------
// Kernel 3: bias_wl[h][i][j] = wl*(z[i,j,:]@Wb[:,h] + bb[h])
// Block = (j-tile of 64) x (i). z tile staged in LDS (row pad 129).
// ---------------------------------------------------------------------------
__global__ __launch_bounds__(256) void bias_kernel(
    const float* __restrict__ z, const float* __restrict__ Wb,
    const float* __restrict__ bb, float* __restrict__ bias_wl)
{
    int i  = blockIdx.y;
    int j0 = blockIdx.x * 64;
    __shared__ float sZ[64 * 129];
    __shared__ float sWb[CZ * NH];
    __shared__ float sbb[NH];
    int t = threadIdx.x;
    for (int e = t; e < CZ * NH; e += 256) sWb[e] = Wb[e];
    if (t < NH) sbb[t] = bb[t];
    #pragma unroll
    for (int q = 0; q < 32; q++) {
        int e = t + 256 * q;
        int jl = e >> 7, c = e & 127;
        sZ[jl * 129 + c] = z[(size_t)(i * NRES + j0 + jl) * CZ + c];
    }
    __syncthreads();
    int jl = t & 63, hg = t >> 6;       // hg in 0..3 -> heads 3*hg..3*hg+2
    float acc0 = 0.f, acc1 = 0.f, acc2 = 0.f;
    for (int c = 0; c < CZ; c++) {
        float zv = sZ[jl * 129 + c];
        acc0 += zv * sWb[c * NH + hg * 3 + 0];
        acc1 += zv * sWb[c * NH + hg * 3 + 1];
        acc2 += zv * sWb[c * NH + hg * 3 + 2];
    }
    int h0 = hg * 3;
    bias_wl[(size_t)((h0 + 0) * NRES + i) * NRES + j0 + jl] = WLc * (acc0 + sbb[h0 + 0]);
    bias_wl[(size_t)((h0 + 1) * NRES + i) * NRES + j0 + jl] = WLc * (acc1 + sbb[h0 + 1]);
    bias_wl[(size_t)((h0 + 2) * NRES + i) * NRES + j0 + jl] = WLc * (acc2 + sbb[h0 + 2]);
}

// ---------------------------------------------------------------------------
// Kernel 4: attention. One block per residue i, 256 threads (4 waves).
// logits (32-dot + bias) -> softmax (per-wave) -> v/vp outputs -> pairwise.
// Writes the full 2112-wide concat row.
// ---------------------------------------------------------------------------
__global__ __launch_bounds__(256) void attn_kernel(
    const float* __restrict__ z, const float* __restrict__ T,
    float* __restrict__ ws)
{
    int i    = blockIdx.x;
    int t    = threadIdx.x;
    int lane = t & 63, w = t >> 6;

    __shared__ float sQe[NH * 32];
    __shared__ float sT16[16];
    __shared__ float sAtt[NH * NRES];     // logits -> att
    __shared__ float sOut[NH * 40];
    __shared__ float sRed[384 * 33];      // union: Ke tile (12672) / pairwise partials (6144)

    const float* Qe      = ws + OFF_QE;
    const float* Ke      = ws + OFF_KE;
    const float* Ve      = ws + OFF_VE;
    const float* bias_wl = ws + OFF_BIAS;
    float* crow          = ws + OFF_CAT + (size_t)i * 2112;

    if (t < 16) sT16[t] = T[i * 16 + t];
    for (int e = t; e < NH * 32; e += 256)
        sQe[e] = Qe[(size_t)((e >> 5) * NRES + i) * 32 + (e & 31)];

    // ---- logits ----
    for (int h = 0; h < NH; h++) {
        __syncthreads();
        for (int e = t; e < NRES * 32; e += 256) {
            int j = e >> 5, c = e & 31;
            sRed[j * 33 + c] = Ke[(size_t)(h * NRES + j) * 32 + c];
        }
        __syncthreads();
        for (int j = t; j < NRES; j += 256) {
            float acc = 0.f;
            #pragma unroll
            for (int c = 0; c < 32; c++) acc += sQe[h * 32 + c] * sRed[j * 33 + c];
            sAtt[h * NRES + j] = acc + bias_wl[(size_t)(h * NRES + i) * NRES + j];
        }
    }
    __syncthreads();

    // ---- softmax: wave w handles heads 3w..3w+2 ----
    for (int u = 0; u < 3; u++) {
        int h = w * 3 + u;
        float v[6];
        float mx = -1e30f;
        #pragma unroll
        for (int m = 0; m < 6; m++) { v[m] = sAtt[h * NRES + lane + 64 * m]; mx = fmaxf(mx, v[m]); }
        #pragma unroll
        for (int off = 32; off > 0; off >>= 1) mx = fmaxf(mx, __shfl_down(mx, off));
        mx = __shfl(mx, 0);
        float sum = 0.f;
        #pragma unroll
        for (int m = 0; m < 6; m++) { v[m] = expf(v[m] - mx); sum += v[m]; }
        #pragma unroll
        for (int off = 32; off > 0; off >>= 1) sum += __shfl_down(sum, off);
        sum = __shfl(sum, 0);
        float inv = 1.0f / sum;
        #pragma unroll
        for (int m = 0; m < 6; m++) sAtt[h * NRES + lane + 64 * m] = v[m] * inv;
    }
    __syncthreads();

    // ---- v_out + attended points: out40[h][0:40] = sum_j att * Vext ----
    for (int o = t; o < NH * 40; o += 256) {
        int h = o / 40, c = o % 40;
        const float* vp = Ve + (size_t)(h * NRES) * 40 + c;
        float acc = 0.f;
        for (int j = 0; j < NRES; j++) acc += sAtt[h * NRES + j] * vp[(size_t)j * 40];
        sOut[o] = acc;
    }
    __syncthreads();

    if (t < 192) crow[t] = sOut[(t >> 4) * 40 + (t & 15)];
    if (t < 96) {
        int h = t >> 3, p = t & 7;
        float x0 = sOut[h * 40 + 16 + p * 3 + 0] - sT16[3];
        float x1 = sOut[h * 40 + 16 + p * 3 + 1] - sT16[7];
        float x2 = sOut[h * 40 + 16 + p * 3 + 2] - sT16[11];
        // R^T * x
        float r0 = sT16[0] * x0 + sT16[4] * x1 + sT16[8]  * x2;
        float r1 = sT16[1] * x0 + sT16[5] * x1 + sT16[9]  * x2;
        float r2 = sT16[2] * x0 + sT16[6] * x1 + sT16[10] * x2;
        crow[192 + 0 * 96 + h * 8 + p] = r0;
        crow[192 + 1 * 96 + h * 8 + p] = r1;
        crow[192 + 2 * 96 + h * 8 + p] = r2;
        crow[480 + h * 8 + p] = sqrtf(r0 * r0 + r1 * r1 + r2 * r2);
    }

    // ---- pairwise: pw[h][c] = sum_j att[h][j] * z[i][j][c] ----
    float2 acc[NH];
    #pragma unroll
    for (int h = 0; h < NH; h++) { acc[h].x = 0.f; acc[h].y = 0.f; }
    for (int jj = 0; jj < 96; jj++) {
        int j = w + 4 * jj;
        float2 zv = *(const float2*)&z[(size_t)(i * NRES + j) * CZ + 2 * lane];
        #pragma unroll
        for (int h = 0; h < NH; h++) {
            float a = sAtt[h * NRES + j];
            acc[h].x += a * zv.x;
            acc[h].y += a * zv.y;
        }
    }
    #pragma unroll
    for (int h = 0; h < NH; h++) {
        sRed[(w * NH + h) * CZ + 2 * lane]     = acc[h].x;
        sRed[(w * NH + h) * CZ + 2 * lane + 1] = acc[h].y;
    }
    __syncthreads();
    for (int o = t; o < NH * CZ; o += 256)
        crow[576 + o] = sRed[o] + sRed[1536 + o] + sRed[2 * 1536 + o] + sRed[3 * 1536 + o];
}

// ---------------------------------------------------------------------------
// Kernel 5: init output with bo
// ---------------------------------------------------------------------------
__global__ __launch_bounds__(256) void out_init(const float* __restrict__ bo, float* __restrict__ out)
{
    int idx = blockIdx.x * 256 + threadIdx.x;
    if (idx < NRES * CS) out[idx] = bo[idx % CS];
}

// ---------------------------------------------------------------------------
// Kernel 6: out += concat(384x2112) @ Wo(2112x384). K-split 4, atomicAdd.
// ---------------------------------------------------------------------------
__global__ __launch_bounds__(256) void out_gemm(
    const float* __restrict__ concat, const float* __restrict__ Wo,
    float* __restrict__ out)
{
    __shared__ float sA[16][33];
    __shared__ float sB[16][33];
    int t  = threadIdx.x;
    int tx = t & 15, ty = t >> 4;
    int n0 = blockIdx.x * 32, m0 = blockIdx.y * 32;
    int kbase = blockIdx.z * 528;
    float acc00 = 0.f, acc01 = 0.f, acc10 = 0.f, acc11 = 0.f;

    for (int k0 = kbase; k0 < kbase + 528; k0 += 16) {
        __syncthreads();
        #pragma unroll
        for (int q = 0; q < 2; q++) {
            int e  = t + 256 * q;
            int il = e >> 4, kl = e & 15;
            sA[kl][il] = concat[(size_t)(m0 + il) * 2112 + k0 + kl];
            int kl2 = e >> 5, jl = e & 31;
            sB[kl2][jl] = Wo[(size_t)(k0 + kl2) * CS + n0 + jl];
        }
        __syncthreads();
        #pragma unroll
        for (int k = 0; k < 16; k++) {
            float a0 = sA[k][ty * 2], a1 = sA[k][ty * 2 + 1];
            float b0 = sB[k][tx * 2], b1 = sB[k][tx * 2 + 1];
            acc00 += a0 * b0; acc01 += a0 * b1;
            acc10 += a1 * b0; acc11 += a1 * b1;
        }
    }
    atomicAdd(&out[(size_t)(m0 + ty * 2 + 0) * CS + n0 + tx * 2 + 0], acc00);
    atomicAdd(&out[(size_t)(m0 + ty * 2 + 0) * CS + n0 + tx * 2 + 1], acc01);
    atomicAdd(&out[(size_t)(m0 + ty * 2 + 1) * CS + n0 + tx * 2 + 0], acc10);
    atomicAdd(&out[(size_t)(m0 + ty * 2 + 1) * CS + n0 + tx * 2 + 1], acc11);
}

extern "C" void kernel_launch(void* const* d_in, const int* in_sizes, int n_in,
                              void* d_out, int out_size, void* d_ws, size_t ws_size,
                              hipStream_t stream)
{
    const float* s   = (const float*)d_in[0];
    const float* z   = (const float*)d_in[1];
    const float* T   = (const float*)d_in[2];
    const float* Wq  = (const float*)d_in[3];
    const float* bq  = (const float*)d_in[4];
    const float* Wk  = (const float*)d_in[5];
    const float* bk  = (const float*)d_in[6];
    const float* Wv  = (const float*)d_in[7];
    const float* bv  = (const float*)d_in[8];
    const float* Wqp = (const float*)d_in[9];
    const float* bqp = (const float*)d_in[10];
    const float* Wkp = (const float*)d_in[11];
    const float* bkp = (const float*)d_in[12];
    const float* Wvp = (const float*)d_in[13];
    const float* bvp = (const float*)d_in[14];
    const float* Wb  = (const float*)d_in[15];
    const float* bb  = (const float*)d_in[16];
    const float* Wo  = (const float*)d_in[17];
    const float* bo  = (const float*)d_in[18];
    const float* hw  = (const float*)d_in[19];
    float* ws  = (float*)d_ws;
    float* out = (float*)d_out;

    proj_kernel<<<dim3(37, 12), 256, 0, stream>>>(s, Wq, bq, Wk, bk, Wv, bv,
                                                  Wqp, bqp, Wkp, bkp, Wvp, bvp, ws);
    prep_kernel<<<18, 256, 0, stream>>>(T, hw, ws);
    bias_kernel<<<dim3(6, NRES), 256, 0, stream>>>(z, Wb, bb, ws + OFF_BIAS);
    attn_kernel<<<NRES, 256, 0, stream>>>(z, T, ws);
    out_init<<<576, 256, 0, stream>>>(bo, out);
    out_gemm<<<dim3(12, 12, 4), 256, 0, stream>>>(ws + OFF_CAT, Wo, out);
}

// Round 2
// 241.024 us; speedup vs baseline: 1.3212x; 1.3212x over previous
//
#include <hip/hip_runtime.h>
#include <math.h>

#define NRES 384
#define NH   12
#define WLc 0.5773502691896258f
#define WCc 0.23570226039551587f

typedef __attribute__((ext_vector_type(8))) short short8;
typedef __attribute__((ext_vector_type(4))) float f32x4;

// workspace layout (float offsets). Region 0 is time-shared:
//   P (proj out, 442368 f32) lives [proj..prep]; bias_bf16 (884736 f-slots)
//   written after prep by bias_mfma. Disjoint lifetimes.
#define OFF_P    0
#define OFF_BIASB 0          // ushort[1769472] = bias_wl bf16 [h][i][j]
#define OFF_QE   884736      // f32 [12][384][32]
#define OFF_KE   1032192     // f32 [12][384][32]
#define OFF_VET  1179648     // ushort [12][48][384]
#define OFF_O40  1290240     // f32 [384][480]  (12h x 40c)
#define OFF_SBF  1474560     // ushort [384][384]  s bf16
#define OFF_WCT  1548288     // ushort [1152][384] Wcat^T bf16
#define OFF_BCT  1769472     // f32 [1152]
#define OFF_WOT  1770624     // ushort [384][2112] Wo^T bf16
#define OFF_CAT  2176128     // ushort [384][2112] concat bf16
#define OFF_ATT  2581632     // ushort [12][384][384] att bf16
// end 3466368 floats = 13,865,472 B  (<= round-1's proven 14.0 MB)

__device__ inline unsigned short f2bf(float f) {
    union { float f; unsigned u; } v; v.f = f;
    unsigned u = v.u;
    return (unsigned short)((u + 0x7FFFu + ((u >> 16) & 1u)) >> 16);
}
__device__ inline float bf2f(unsigned short h) {
    union { unsigned u; float f; } v; v.u = ((unsigned)h) << 16;
    return v.f;
}

// ---------------------------------------------------------------------------
// K0: pack/convert: s->bf16; Wcat^T bf16; Wo^T bf16; bcat f32
// ---------------------------------------------------------------------------
__global__ __launch_bounds__(256) void pack_kernel(
    const float* __restrict__ s,
    const float* __restrict__ Wq,  const float* __restrict__ bq,
    const float* __restrict__ Wk,  const float* __restrict__ bk,
    const float* __restrict__ Wv,  const float* __restrict__ bv,
    const float* __restrict__ Wqp, const float* __restrict__ bqp,
    const float* __restrict__ Wkp, const float* __restrict__ bkp,
    const float* __restrict__ Wvp, const float* __restrict__ bvp,
    const float* __restrict__ Wo,
    float* __restrict__ ws)
{
    int id = blockIdx.x * 256 + threadIdx.x;
    unsigned short* sbf  = (unsigned short*)(ws + OFF_SBF);
    unsigned short* wct  = (unsigned short*)(ws + OFF_WCT);
    unsigned short* wot  = (unsigned short*)(ws + OFF_WOT);
    float* bct = ws + OFF_BCT;

    if (id < 36864) {                      // s -> bf16, 4 elems each
        const float4 v = ((const float4*)s)[id];
        unsigned short r[4] = { f2bf(v.x), f2bf(v.y), f2bf(v.z), f2bf(v.w) };
        *(uint2*)(sbf + id * 4) = *(uint2*)r;
        return;
    }
    id -= 36864;
    if (id < 55296) {                      // Wcat^T: (n, k8)
        int n = id / 48, k8 = (id % 48) * 8;
        const float* W; int dout, col;
        if      (n < 192) { W = Wq;  dout = 192; col = n; }
        else if (n < 384) { W = Wk;  dout = 192; col = n - 192; }
        else if (n < 576) { W = Wv;  dout = 192; col = n - 384; }
        else if (n < 720) { W = Wqp; dout = 144; col = n - 576; }
        else if (n < 864) { W = Wkp; dout = 144; col = n - 720; }
        else              { W = Wvp; dout = 288; col = n - 864; }
        unsigned short r[8];
        #pragma unroll
        for (int j = 0; j < 8; j++) r[j] = f2bf(W[(size_t)(k8 + j) * dout + col]);
        *(uint4*)(wct + (size_t)n * 384 + k8) = *(uint4*)r;
        return;
    }
    id -= 55296;
    if (id < 101376) {                     // Wo^T: (n, k8)
        int n = id / 264, k8 = (id % 264) * 8;
        unsigned short r[8];
        #pragma unroll
        for (int j = 0; j < 8; j++) r[j] = f2bf(Wo[(size_t)(k8 + j) * 384 + n]);
        *(uint4*)(wot + (size_t)n * 2112 + k8) = *(uint4*)r;
        return;
    }
    id -= 101376;
    if (id < 1152) {                       // bcat
        int n = id; float b;
        if      (n < 192) b = bq[n];
        else if (n < 384) b = bk[n - 192];
        else if (n < 576) b = bv[n - 384];
        else if (n < 720) b = bqp[n - 576];
        else if (n < 864) b = bkp[n - 720];
        else              b = bvp[n - 864];
        bct[n] = b;
    }
}

// ---------------------------------------------------------------------------
// K1: proj MFMA: P(384x1152) = s_bf @ Wcat + bcat   (direct-global fragments)
// grid (18 n-tiles of 64, 6 m-tiles of 64), 256 thr
// ---------------------------------------------------------------------------
__global__ __launch_bounds__(256) void proj_mfma(float* __restrict__ ws)
{
    const unsigned short* sbf = (const unsigned short*)(ws + OFF_SBF);
    const unsigned short* wct = (const unsigned short*)(ws + OFF_WCT);
    const float* bct = ws + OFF_BCT;
    float* P = ws + OFF_P;

    int t = threadIdx.x, w = t >> 6, lane = t & 63;
    int m = lane & 15, q = lane >> 4;
    int n0 = blockIdx.x * 64, m0 = blockIdx.y * 64 + w * 16;

    f32x4 acc[4] = {0};
    const unsigned short* arow = sbf + (size_t)(m0 + m) * 384;
    #pragma unroll 4
    for (int s = 0; s < 12; s++) {
        int k = s * 32 + q * 8;
        short8 a = *(const short8*)(arow + k);
        #pragma unroll
        for (int nt = 0; nt < 4; nt++) {
            short8 b = *(const short8*)(wct + (size_t)(n0 + nt * 16 + m) * 384 + k);
            acc[nt] = __builtin_amdgcn_mfma_f32_16x16x32_bf16(a, b, acc[nt], 0, 0, 0);
        }
    }
    #pragma unroll
    for (int nt = 0; nt < 4; nt++) {
        int col = n0 + nt * 16 + m;
        float bias = bct[col];
        #pragma unroll
        for (int r = 0; r < 4; r++) {
            int row = m0 + q * 4 + r;
            P[(size_t)row * 1152 + col] = acc[nt][r] + bias;
        }
    }
}

// ---------------------------------------------------------------------------
// K2: prep — Qe/Ke fp32 (32-dim extended), Ve_t bf16 [h][48][384]
// ---------------------------------------------------------------------------
__global__ __launch_bounds__(256) void prep_kernel(
    const float* __restrict__ T, const float* __restrict__ hw,
    float* __restrict__ ws)
{
    int id = blockIdx.x * 256 + threadIdx.x;
    if (id >= NH * NRES) return;
    int h = id / NRES, i = id % NRES;
    const float* P = ws + OFF_P;
    const float* pr = P + (size_t)i * 1152;

    float R[3][3], tr[3];
    #pragma unroll
    for (int r = 0; r < 3; r++) {
        #pragma unroll
        for (int c = 0; c < 3; c++) R[r][c] = T[i * 16 + r * 4 + c];
        tr[r] = T[i * 16 + r * 4 + 3];
    }
    float x = hw[h];
    float g = (x > 20.f) ? x : log1pf(expf(x));

    float* Qe = ws + OFF_QE + (size_t)(h * NRES + i) * 32;
    float* Ke = ws + OFF_KE + (size_t)(h * NRES + i) * 32;
    #pragma unroll
    for (int c = 0; c < 16; c++) {
        Qe[c] = WLc * 0.25f * pr[h * 16 + c];
        Ke[c] = pr[192 + h * 16 + c];
    }
    float sqq = 0.f, sqk = 0.f;
    float gw = WLc * g * WCc;
    #pragma unroll
    for (int p = 0; p < 4; p++) {
        float a0 = pr[576 + 0 * 48 + h * 4 + p];
        float a1 = pr[576 + 1 * 48 + h * 4 + p];
        float a2 = pr[576 + 2 * 48 + h * 4 + p];
        float b0 = pr[720 + 0 * 48 + h * 4 + p];
        float b1 = pr[720 + 1 * 48 + h * 4 + p];
        float b2 = pr[720 + 2 * 48 + h * 4 + p];
        #pragma unroll
        for (int r = 0; r < 3; r++) {
            float tq = R[r][0] * a0 + R[r][1] * a1 + R[r][2] * a2 + tr[r];
            float tk = R[r][0] * b0 + R[r][1] * b1 + R[r][2] * b2 + tr[r];
            Qe[16 + p * 3 + r] = gw * tq;
            Ke[16 + p * 3 + r] = tk;
            sqq += tq * tq;  sqk += tk * tk;
        }
    }
    Qe[28] = -0.5f * gw;  Qe[29] = -0.5f * gw * sqq;  Qe[30] = 0.f; Qe[31] = 0.f;
    Ke[28] = sqk;         Ke[29] = 1.f;               Ke[30] = 0.f; Ke[31] = 0.f;

    unsigned short* vet = (unsigned short*)(ws + OFF_VET);
    #pragma unroll
    for (int c = 0; c < 16; c++)
        vet[(size_t)(h * 48 + c) * 384 + i] = f2bf(pr[384 + h * 16 + c]);
    #pragma unroll
    for (int p = 0; p < 8; p++) {
        float a0 = pr[864 + 0 * 96 + h * 8 + p];
        float a1 = pr[864 + 1 * 96 + h * 8 + p];
        float a2 = pr[864 + 2 * 96 + h * 8 + p];
        #pragma unroll
        for (int r = 0; r < 3; r++)
            vet[(size_t)(h * 48 + 16 + p * 3 + r) * 384 + i] =
                f2bf(R[r][0] * a0 + R[r][1] * a1 + R[r][2] * a2 + tr[r]);
    }
    #pragma unroll
    for (int c = 40; c < 48; c++) vet[(size_t)(h * 48 + c) * 384 + i] = 0;
}

// ---------------------------------------------------------------------------
// K3: bias MFMA: bias_bf[h][ij] = bf16(wl*(z@Wb + bb))  M=147456,N=16,K=128
// 2304 blocks (64-row tiles), 256 thr
// ---------------------------------------------------------------------------
__global__ __launch_bounds__(256) void bias_mfma(
    const float* __restrict__ z, const float* __restrict__ Wb,
    const float* __restrict__ bb, float* __restrict__ ws)
{
    __shared__ unsigned short zb[64 * 136];
    __shared__ unsigned short wbT[16 * 136];
    __shared__ float sbb[16];
    unsigned short* biasb = (unsigned short*)(ws + OFF_BIASB);

    int t = threadIdx.x;
    size_t m0 = (size_t)blockIdx.x * 64;

    {   // stage z tile 64x128 -> bf16 LDS
        int r = t >> 2, co = (t & 3) * 32;
        const float* zr = z + (m0 + r) * 128 + co;
        #pragma unroll
        for (int u = 0; u < 4; u++) {
            float4 v0 = ((const float4*)zr)[u * 2 + 0];
            float4 v1 = ((const float4*)zr)[u * 2 + 1];
            unsigned short rr[8] = { f2bf(v0.x), f2bf(v0.y), f2bf(v0.z), f2bf(v0.w),
                                     f2bf(v1.x), f2bf(v1.y), f2bf(v1.z), f2bf(v1.w) };
            *(uint4*)(zb + r * 136 + co + u * 8) = *(uint4*)rr;
        }
    }
    if (t < 128) {
        #pragma unroll
        for (int h = 0; h < 12; h++) wbT[h * 136 + t] = f2bf(Wb[t * 12 + h]);
        #pragma unroll
        for (int h = 12; h < 16; h++) wbT[h * 136 + t] = 0;
    }
    if (t < 16) sbb[t] = (t < 12) ? bb[t] : 0.f;
    __syncthreads();

    int w = t >> 6, lane = t & 63;
    int m = lane & 15, q = lane >> 4;
    f32x4 acc = {0};
    #pragma unroll
    for (int s = 0; s < 4; s++) {
        int k = s * 32 + q * 8;
        short8 a = *(const short8*)(zb + (w * 16 + m) * 136 + k);
        short8 b = *(const short8*)(wbT + m * 136 + k);
        acc = __builtin_amdgcn_mfma_f32_16x16x32_bf16(a, b, acc, 0, 0, 0);
    }
    int h = m;
    if (h < 12) {
        #pragma unroll
        for (int r = 0; r < 4; r++) {
            size_t ri = m0 + w * 16 + q * 4 + r;
            biasb[(size_t)h * 147456 + ri] = f2bf(WLc * (acc[r] + sbb[h]));
        }
    }
}

// ---------------------------------------------------------------------------
// K4: logits + softmax (fp32), writes att bf16. grid (48 i-tiles, 12 h), 512 thr
// ---------------------------------------------------------------------------
__global__ __launch_bounds__(512) void logits_kernel(float* __restrict__ ws)
{
    __shared__ float sQe[8 * 32];
    __shared__ float sLg[8][384];
    __shared__ float sMS[16];

    int h = blockIdx.y, i0 = blockIdx.x * 8;
    int t = threadIdx.x;
    const float* Qe = ws + OFF_QE;
    const float* Ke = ws + OFF_KE;
    const unsigned short* biasb = (const unsigned short*)(ws + OFF_BIASB);
    unsigned short* attb = (unsigned short*)(ws + OFF_ATT);

    if (t < 256)
        sQe[t] = Qe[(size_t)(h * 384 + i0 + (t >> 5)) * 32 + (t & 31)];
    __syncthreads();

    float lgv[8];
    if (t < 384) {
        int j = t;
        float ke[32];
        const float4* kr = (const float4*)(Ke + (size_t)(h * 384 + j) * 32);
        #pragma unroll
        for (int u = 0; u < 8; u++) { float4 v = kr[u]; ke[u*4]=v.x; ke[u*4+1]=v.y; ke[u*4+2]=v.z; ke[u*4+3]=v.w; }
        #pragma unroll
        for (int ii = 0; ii < 8; ii++) {
            float acc = 0.f;
            #pragma unroll
            for (int c = 0; c < 32; c++) acc += sQe[ii * 32 + c] * ke[c];
            acc += bf2f(biasb[(size_t)(h * 384 + i0 + ii) * 384 + j]);
            lgv[ii] = acc;
            sLg[ii][j] = acc;
        }
    }
    __syncthreads();
    {
        int w = t >> 6, lane = t & 63;   // wave w owns row ii=w
        float vv[6], mx = -1e30f;
        #pragma unroll
        for (int u = 0; u < 6; u++) { vv[u] = sLg[w][lane + 64 * u]; mx = fmaxf(mx, vv[u]); }
        #pragma unroll
        for (int off = 1; off < 64; off <<= 1) mx = fmaxf(mx, __shfl_xor(mx, off));
        float sm = 0.f;
        #pragma unroll
        for (int u = 0; u < 6; u++) sm += __expf(vv[u] - mx);
        #pragma unroll
        for (int off = 1; off < 64; off <<= 1) sm += __shfl_xor(sm, off);
        if (lane == 0) { sMS[w] = mx; sMS[8 + w] = sm; }
    }
    __syncthreads();
    if (t < 384) {
        int j = t;
        #pragma unroll
        for (int ii = 0; ii < 8; ii++) {
            float a = __expf(lgv[ii] - sMS[ii]) * (1.0f / sMS[8 + ii]);
            attb[(size_t)(h * 384 + i0 + ii) * 384 + j] = f2bf(a);
        }
    }
}

// ---------------------------------------------------------------------------
// K5: out40 MFMA: att[h](384x384) @ Ve_t[h]^T -> out40_raw[i][h*40+c]
// grid (12 m-tiles of 32, 12 h), 128 thr (2 waves)
// ---------------------------------------------------------------------------
__global__ __launch_bounds__(128) void out40_mfma(float* __restrict__ ws)
{
    const unsigned short* attb = (const unsigned short*)(ws + OFF_ATT);
    const unsigned short* vet  = (const unsigned short*)(ws + OFF_VET);
    float* o40 = ws + OFF_O40;

    int h = blockIdx.y;
    int t = threadIdx.x, w = t >> 6, lane = t & 63;
    int m = lane & 15, q = lane >> 4;
    int m0 = blockIdx.x * 32 + w * 16;

    f32x4 acc[3] = {0};
    const unsigned short* arow = attb + (size_t)(h * 384 + m0 + m) * 384;
    #pragma unroll 3
    for (int s = 0; s < 12; s++) {
        int k = s * 32 + q * 8;
        short8 a = *(const short8*)(arow + k);
        #pragma unroll
        for (int nt = 0; nt < 3; nt++) {
            short8 b = *(const short8*)(vet + (size_t)(h * 48 + nt * 16 + m) * 384 + k);
            acc[nt] = __builtin_amdgcn_mfma_f32_16x16x32_bf16(a, b, acc[nt], 0, 0, 0);
        }
    }
    #pragma unroll
    for (int nt = 0; nt < 3; nt++) {
        int c = nt * 16 + m;
        if (c < 40) {
            #pragma unroll
            for (int r = 0; r < 4; r++) {
                int row = m0 + q * 4 + r;
                o40[(size_t)row * 480 + h * 40 + c] = acc[nt][r];
            }
        }
    }
}

// ---------------------------------------------------------------------------
// K6: pairwise MFMA per i (att_i(16x384) @ z_i(384x128)) + point epilogue.
// 384 blocks, 256 thr. Writes full concat row (bf16, 2112 cols).
// ---------------------------------------------------------------------------
__global__ __launch_bounds__(256) void pairwise_pts(
    const float* __restrict__ z, const float* __restrict__ T,
    float* __restrict__ ws)
{
    __shared__ unsigned short zt[128 * 40];
    __shared__ float sT16[16];

    int i = blockIdx.x;
    int t = threadIdx.x, w = t >> 6, lane = t & 63;
    int m = lane & 15, q = lane >> 4;
    const unsigned short* attb = (const unsigned short*)(ws + OFF_ATT);
    unsigned short* catb = (unsigned short*)(ws + OFF_CAT) ;
    const float* o40 = ws + OFF_O40;

    if (t < 16) sT16[t] = T[i * 16 + t];

    f32x4 acc0 = {0}, acc1 = {0};
    int cst = t & 63, jg = t >> 6;
    for (int kt = 0; kt < 12; kt++) {
        int j0 = kt * 32;
        __syncthreads();
        {   // stage z[i][j0..j0+31][:] -> zt[c][j] bf16 (transposed)
            int j8 = j0 + jg * 8;
            const float* zb = z + ((size_t)i * 384 + j8) * 128 + cst;
            unsigned short r0[8], r1[8];
            #pragma unroll
            for (int jj = 0; jj < 8; jj++) {
                r0[jj] = f2bf(zb[(size_t)jj * 128]);
                r1[jj] = f2bf(zb[(size_t)jj * 128 + 64]);
            }
            *(uint4*)(zt + cst * 40 + jg * 8)        = *(uint4*)r0;
            *(uint4*)(zt + (cst + 64) * 40 + jg * 8) = *(uint4*)r1;
        }
        __syncthreads();
        short8 a;
        if (m < 12) a = *(const short8*)(attb + ((size_t)(m * 384 + i)) * 384 + j0 + q * 8);
        else        a = (short8){0,0,0,0,0,0,0,0};
        short8 b0 = *(const short8*)(zt + (w * 32 + m) * 40 + q * 8);
        short8 b1 = *(const short8*)(zt + (w * 32 + 16 + m) * 40 + q * 8);
        acc0 = __builtin_amdgcn_mfma_f32_16x16x32_bf16(a, b0, acc0, 0, 0, 0);
        acc1 = __builtin_amdgcn_mfma_f32_16x16x32_bf16(a, b1, acc1, 0, 0, 0);
    }
    {   // pairwise -> concat cols 576..2111
        unsigned short* crow = catb + (size_t)i * 2112 + 576;
        #pragma unroll
        for (int r = 0; r < 4; r++) {
            int h = q * 4 + r;
            if (h < 12) {
                crow[h * 128 + w * 32 + m]      = f2bf(acc0[r]);
                crow[h * 128 + w * 32 + 16 + m] = f2bf(acc1[r]);
            }
        }
    }
    __syncthreads();
    // epilogue: v_out copy + inverse-warp points + norms
    if (t < 192)
        catb[(size_t)i * 2112 + t] = f2bf(o40[(size_t)i * 480 + (t >> 4) * 40 + (t & 15)]);
    if (t < 96) {
        int h = t >> 3, p = t & 7;
        const float* o = o40 + (size_t)i * 480 + h * 40 + 16 + p * 3;
        float x0 = o[0] - sT16[3];
        float x1 = o[1] - sT16[7];
        float x2 = o[2] - sT16[11];
        float r0 = sT16[0] * x0 + sT16[4] * x1 + sT16[8]  * x2;
        float r1 = sT16[1] * x0 + sT16[5] * x1 + sT16[9]  * x2;
        float r2 = sT16[2] * x0 + sT16[6] * x1 + sT16[10] * x2;
        unsigned short* crow = catb + (size_t)i * 2112;
        crow[192 + 0 * 96 + h * 8 + p] = f2bf(r0);
        crow[192 + 1 * 96 + h * 8 + p] = f2bf(r1);
        crow[192 + 2 * 96 + h * 8 + p] = f2bf(r2);
        crow[480 + h * 8 + p] = f2bf(sqrtf(r0 * r0 + r1 * r1 + r2 * r2));
    }
}

// ---------------------------------------------------------------------------
// K7: out init with bo
// ---------------------------------------------------------------------------
__global__ __launch_bounds__(256) void out_init(const float* __restrict__ bo, float* __restrict__ out)
{
    int idx = blockIdx.x * 256 + threadIdx.x;
    if (idx < 384 * 384) out[idx] = bo[idx % 384];
}

// ---------------------------------------------------------------------------
// K8: out GEMM MFMA: concat(384x2112) @ Wo + atomic accumulate (k-split 3)
// grid (6,6,3), 256 thr
// ---------------------------------------------------------------------------
__global__ __launch_bounds__(256) void outgemm_mfma(float* __restrict__ ws, float* __restrict__ out)
{
    const unsigned short* catb = (const unsigned short*)(ws + OFF_CAT);
    const unsigned short* wot  = (const unsigned short*)(ws + OFF_WOT);

    int t = threadIdx.x, w = t >> 6, lane = t & 63;
    int m = lane & 15, q = lane >> 4;
    int n0 = blockIdx.x * 64, m0 = blockIdx.y * 64 + w * 16;
    int kbase = blockIdx.z * 704;

    f32x4 acc[4] = {0};
    const unsigned short* arow = catb + (size_t)(m0 + m) * 2112;
    #pragma unroll 2
    for (int s = 0; s < 22; s++) {
        int k = kbase + s * 32 + q * 8;
        short8 a = *(const short8*)(arow + k);
        #pragma unroll
        for (int nt = 0; nt < 4; nt++) {
            short8 b = *(const short8*)(wot + (size_t)(n0 + nt * 16 + m) * 2112 + k);
            acc[nt] = __builtin_amdgcn_mfma_f32_16x16x32_bf16(a, b, acc[nt], 0, 0, 0);
        }
    }
    #pragma unroll
    for (int nt = 0; nt < 4; nt++) {
        int col = n0 + nt * 16 + m;
        #pragma unroll
        for (int r = 0; r < 4; r++) {
            int row = m0 + q * 4 + r;
            atomicAdd(&out[(size_t)row * 384 + col], acc[nt][r]);
        }
    }
}

extern "C" void kernel_launch(void* const* d_in, const int* in_sizes, int n_in,
                              void* d_out, int out_size, void* d_ws, size_t ws_size,
                              hipStream_t stream)
{
    const float* s   = (const float*)d_in[0];
    const float* z   = (const float*)d_in[1];
    const float* T   = (const float*)d_in[2];
    const float* Wq  = (const float*)d_in[3];
    const float* bq  = (const float*)d_in[4];
    const float* Wk  = (const float*)d_in[5];
    const float* bk  = (const float*)d_in[6];
    const float* Wv  = (const float*)d_in[7];
    const float* bv  = (const float*)d_in[8];
    const float* Wqp = (const float*)d_in[9];
    const float* bqp = (const float*)d_in[10];
    const float* Wkp = (const float*)d_in[11];
    const float* bkp = (const float*)d_in[12];
    const float* Wvp = (const float*)d_in[13];
    const float* bvp = (const float*)d_in[14];
    const float* Wb  = (const float*)d_in[15];
    const float* bb  = (const float*)d_in[16];
    const float* Wo  = (const float*)d_in[17];
    const float* bo  = (const float*)d_in[18];
    const float* hw  = (const float*)d_in[19];
    float* ws  = (float*)d_ws;
    float* out = (float*)d_out;

    pack_kernel<<<(36864 + 55296 + 101376 + 1152 + 255) / 256, 256, 0, stream>>>(
        s, Wq, bq, Wk, bk, Wv, bv, Wqp, bqp, Wkp, bkp, Wvp, bvp, Wo, ws);
    proj_mfma<<<dim3(18, 6), 256, 0, stream>>>(ws);
    prep_kernel<<<18, 256, 0, stream>>>(T, hw, ws);
    bias_mfma<<<2304, 256, 0, stream>>>(z, Wb, bb, ws);
    logits_kernel<<<dim3(48, 12), 512, 0, stream>>>(ws);
    out40_mfma<<<dim3(12, 12), 128, 0, stream>>>(ws);
    pairwise_pts<<<384, 256, 0, stream>>>(z, T, ws);
    out_init<<<576, 256, 0, stream>>>(bo, out);
    outgemm_mfma<<<dim3(6, 6, 3), 256, 0, stream>>>(ws, out);
}